// Round 1
// baseline (778.190 us; speedup 1.0000x reference)
//
#include <hip/hip_runtime.h>

#define T_TOK 2048
#define HDIM  2048
#define FDIM  4096
#define NEXP  8

#define BM 128
#define BN 128
#define BK 64
#define BKP 68   // padded BT row stride (elements)

typedef float f32x4 __attribute__((ext_vector_type(4)));
typedef float fvec4 __attribute__((ext_vector_type(4)));
typedef short s16x4 __attribute__((ext_vector_type(4)));
typedef short s16x8 __attribute__((ext_vector_type(8)));

__device__ __forceinline__ short f2bf(float f) {
  union { float f; unsigned u; } c; c.f = f;
  unsigned r = c.u + 0x7FFFu + ((c.u >> 16) & 1u);
  return (short)(r >> 16);
}
__device__ __forceinline__ float bf2f(short h) {
  union { float f; unsigned u; } c; c.u = ((unsigned)(unsigned short)h) << 16;
  return c.f;
}

// ---------------- router: logits + top1 + sigmoid score ----------------
__global__ __launch_bounds__(256) void router_kernel(
    const float* __restrict__ h, const float* __restrict__ rw,
    float* __restrict__ logits, int* __restrict__ eid, float* __restrict__ score)
{
  int tok  = blockIdx.x * 4 + (threadIdx.x >> 6);
  int lane = threadIdx.x & 63;
  float a[8] = {0.f,0.f,0.f,0.f,0.f,0.f,0.f,0.f};
  const float* hp = h + (size_t)tok * HDIM;
  for (int i = lane; i < HDIM; i += 64) {
    float hv = hp[i];
    const fvec4* wp = (const fvec4*)(rw + (size_t)i * NEXP);
    fvec4 w0 = wp[0], w1 = wp[1];
    a[0] += hv * w0.x; a[1] += hv * w0.y; a[2] += hv * w0.z; a[3] += hv * w0.w;
    a[4] += hv * w1.x; a[5] += hv * w1.y; a[6] += hv * w1.z; a[7] += hv * w1.w;
  }
  #pragma unroll
  for (int e = 0; e < 8; e++) {
    #pragma unroll
    for (int off = 32; off; off >>= 1)
      a[e] += __shfl_xor(a[e], off, 64);
  }
  if (lane == 0) {
    float best = a[0]; int bi = 0;
    #pragma unroll
    for (int e = 1; e < 8; e++) if (a[e] > best) { best = a[e]; bi = e; }
    #pragma unroll
    for (int e = 0; e < 8; e++) logits[(size_t)tok * NEXP + e] = a[e];
    eid[tok] = bi;
    score[tok] = 1.0f / (1.0f + __expf(-best));
  }
}

// ---------------- stable counting sort of tokens by expert ----------------
__global__ __launch_bounds__(512) void sort_kernel(
    const int* __restrict__ eid, int* __restrict__ perm, int* __restrict__ ofs)
{
  __shared__ int s_cnt[8];
  __shared__ int s_off[9];
  int w = threadIdx.x >> 6, lane = threadIdx.x & 63;
  int cnt = 0;
  for (int b = 0; b < T_TOK; b += 64) {
    int id = eid[b + lane];
    unsigned long long m = __ballot(id == w);
    cnt += __popcll(m);
  }
  if (lane == 0) s_cnt[w] = cnt;
  __syncthreads();
  if (threadIdx.x == 0) {
    int o = 0;
    for (int e = 0; e < 8; e++) { s_off[e] = o; o += s_cnt[e]; }
    s_off[8] = o;
    for (int e = 0; e < 9; e++) ofs[e] = s_off[e];
  }
  __syncthreads();
  int pos = s_off[w];
  for (int b = 0; b < T_TOK; b += 64) {
    int tokidx = b + lane;
    int id = eid[tokidx];
    unsigned long long m = __ballot(id == w);
    if (id == w) {
      int p = pos + __popcll(m & ((1ull << lane) - 1ull));
      perm[p] = tokidx;
    }
    pos += __popcll(m);
  }
}

// ---------------- build bf16 h and permuted+scaled x ----------------
__global__ __launch_bounds__(256) void build_kernel(
    const float* __restrict__ h, const float* __restrict__ score,
    const int* __restrict__ perm, short* __restrict__ hb, short* __restrict__ xp)
{
  int row = blockIdx.x;
  int t = threadIdx.x;
  const fvec4* s1 = (const fvec4*)(h + (size_t)row * HDIM);
  for (int j = t; j < HDIM/4; j += 256) {
    fvec4 v = s1[j];
    s16x4 o = { f2bf(v.x), f2bf(v.y), f2bf(v.z), f2bf(v.w) };
    *(s16x4*)(hb + (size_t)row * HDIM + j*4) = o;
  }
  int tok = perm[row];
  float s = score[tok];
  const fvec4* s2 = (const fvec4*)(h + (size_t)tok * HDIM);
  for (int j = t; j < HDIM/4; j += 256) {
    fvec4 v = s2[j];
    s16x4 o = { f2bf(v.x*s), f2bf(v.y*s), f2bf(v.z*s), f2bf(v.w*s) };
    *(s16x4*)(xp + (size_t)row * HDIM + j*4) = o;
  }
}

// ---------------- act: silu(gate)*up ----------------
__global__ __launch_bounds__(256) void act_kernel(
    const short* __restrict__ gu, short* __restrict__ act)
{
  size_t idx = ((size_t)blockIdx.x * 256 + threadIdx.x) * 8;  // over [T, F]
  int row = (int)(idx / FDIM);
  int j   = (int)(idx % FDIM);
  s16x8 g8 = *(const s16x8*)(gu + (size_t)row * 2*FDIM + j);
  s16x8 u8 = *(const s16x8*)(gu + (size_t)row * 2*FDIM + FDIM + j);
  s16x8 o;
  #pragma unroll
  for (int i = 0; i < 8; i++) {
    float g = bf2f(g8[i]), u = bf2f(u8[i]);
    float a = (g / (1.0f + __expf(-g))) * u;
    o[i] = f2bf(a);
  }
  *(s16x8*)(act + (size_t)row * FDIM + j) = o;
}

// ---------------- generic (grouped) bf16 MFMA GEMM ----------------
// A: bf16 [M,K] row-major (linear).  B: fp32 [K,N] row-major, per-group base.
// C: bf16 store | fp32 store | fp32 scatter-accumulate (perm on rows).
template<typename CT, bool SCATTER_ACC>
__global__ __launch_bounds__(256, 2) void gemm_kernel(
    const short* __restrict__ A, int lda,
    const float* __restrict__ Bbase, long long bstride, int ldb,
    CT* __restrict__ C, int ldc, int c_col_off,
    const int* __restrict__ gofs, int mt_per_g, int Mtotal, int K,
    const int* __restrict__ perm)
{
  __shared__ short sA[BM*BK];
  __shared__ short sB[BN*BKP];
  int g  = blockIdx.y / mt_per_g;
  int mt = blockIdx.y % mt_per_g;
  int r0 = 0, r1 = Mtotal;
  if (gofs) { r0 = gofs[g]; r1 = gofs[g+1]; }
  int row0 = r0 + mt * BM;
  if (row0 >= r1) return;
  int rows = r1 - row0; if (rows > BM) rows = BM;
  const float* B = Bbase + (size_t)g * (size_t)bstride;
  int n0 = blockIdx.x * BN;

  int t = threadIdx.x;
  int lane = t & 63;
  int wave = t >> 6;
  int wr = (wave >> 1) * 64, wc = (wave & 1) * 64;
  int l16 = lane & 15, lh = lane >> 4;

  int ar  = t >> 3;   // A stage: row group 0..31
  int akb = t & 7;    // A stage: k-chunk 0..7
  int bc  = t & 31;   // B stage: n4 group 0..31
  int bkb = t >> 5;   // B stage: k4 group 0..7

  f32x4 zero4 = {0.f, 0.f, 0.f, 0.f};
  f32x4 acc[4][4];
  #pragma unroll
  for (int m = 0; m < 4; m++)
    #pragma unroll
    for (int n = 0; n < 4; n++) acc[m][n] = zero4;

  for (int k0 = 0; k0 < K; k0 += BK) {
    if (k0) __syncthreads();
    // ---- stage A (bf16, XOR-swizzled k-chunks) ----
    #pragma unroll
    for (int i = 0; i < 4; i++) {
      int row = ar + 32 * i;
      s16x8 v = {0,0,0,0,0,0,0,0};
      if (row < rows)
        v = *(const s16x8*)(A + (size_t)(row0 + row) * lda + k0 + akb * 8);
      *(s16x8*)(&sA[row * BK + ((akb ^ (row & 7)) * 8)]) = v;
    }
    // ---- stage B (fp32 -> bf16, 4x4 register transpose into [BN][BKP]) ----
    #pragma unroll
    for (int rd = 0; rd < 2; rd++) {
      int kl = bkb * 4 + rd * 32;
      const float* bp = B + (size_t)(k0 + kl) * ldb + n0 + bc * 4;
      fvec4 f0 = *(const fvec4*)(bp);
      fvec4 f1 = *(const fvec4*)(bp + ldb);
      fvec4 f2 = *(const fvec4*)(bp + 2 * (size_t)ldb);
      fvec4 f3 = *(const fvec4*)(bp + 3 * (size_t)ldb);
      #pragma unroll
      for (int i2 = 0; i2 < 4; i2++) {
        s16x4 o = { f2bf(f0[i2]), f2bf(f1[i2]), f2bf(f2[i2]), f2bf(f3[i2]) };
        *(s16x4*)(&sB[(bc * 4 + i2) * BKP + kl]) = o;
      }
    }
    __syncthreads();
    // ---- compute ----
    #pragma unroll
    for (int kk = 0; kk < BK; kk += 32) {
      s16x8 aF[4], bF[4];
      #pragma unroll
      for (int m = 0; m < 4; m++) {
        int row = wr + m * 16 + l16;
        int slot = ((kk >> 3) + lh) ^ (row & 7);
        aF[m] = *(const s16x8*)(&sA[row * BK + slot * 8]);
      }
      #pragma unroll
      for (int n = 0; n < 4; n++) {
        int col = wc + n * 16 + l16;
        int kb = kk + lh * 8;
        s16x4 lo = *(const s16x4*)(&sB[col * BKP + kb]);
        s16x4 hi = *(const s16x4*)(&sB[col * BKP + kb + 4]);
        bF[n] = __builtin_shufflevector(lo, hi, 0, 1, 2, 3, 4, 5, 6, 7);
      }
      #pragma unroll
      for (int m = 0; m < 4; m++)
        #pragma unroll
        for (int n = 0; n < 4; n++)
          acc[m][n] = __builtin_amdgcn_mfma_f32_16x16x32_bf16(aF[m], bF[n], acc[m][n], 0, 0, 0);
    }
  }
  // ---- epilogue ----
  #pragma unroll
  for (int m = 0; m < 4; m++) {
    #pragma unroll
    for (int r = 0; r < 4; r++) {
      int lr = wr + m * 16 + lh * 4 + r;
      if (lr >= rows) continue;
      size_t grow;
      if (SCATTER_ACC) grow = (size_t)perm[row0 + lr];
      else             grow = (size_t)(row0 + lr);
      #pragma unroll
      for (int n = 0; n < 4; n++) {
        int gc = n0 + wc + n * 16 + l16;
        size_t off = grow * (size_t)ldc + c_col_off + gc;
        float v = acc[m][n][r];
        if constexpr (SCATTER_ACC) {
          C[off] += v;
        } else if constexpr (sizeof(CT) == 2) {
          C[off] = f2bf(v);
        } else {
          C[off] = v;
        }
      }
    }
  }
}

// ---------------- launch ----------------
extern "C" void kernel_launch(void* const* d_in, const int* in_sizes, int n_in,
                              void* d_out, int out_size, void* d_ws, size_t ws_size,
                              hipStream_t stream)
{
  const float* h   = (const float*)d_in[0];
  const float* rw  = (const float*)d_in[1];
  const float* gup = (const float*)d_in[2];
  const float* dwn = (const float*)d_in[3];
  const float* sg  = (const float*)d_in[4];
  const float* su  = (const float*)d_in[5];
  const float* sd  = (const float*)d_in[6];
  float* out0   = (float*)d_out;                       // [T, H]
  float* logits = out0 + (size_t)T_TOK * HDIM;         // [T, E]

  char* ws = (char*)d_ws;
  int*   eid   = (int*)ws;                  // 2048 ints
  float* score = (float*)(ws + 8192);       // 2048 floats
  int*   perm  = (int*)(ws + 16384);        // 2048 ints
  int*   ofs   = (int*)(ws + 24576);        // 9 ints
  short* hb    = (short*)(ws + 32768);                  // [T, H] bf16
  short* xp    = hb + (size_t)T_TOK * HDIM;             // [T, H] bf16 (perm+scaled)
  short* gu    = xp + (size_t)T_TOK * HDIM;             // [T, 2F] bf16
  short* act   = gu + (size_t)T_TOK * 2 * FDIM;         // [T, F] bf16

  router_kernel<<<T_TOK/4, 256, 0, stream>>>(h, rw, logits, eid, score);
  sort_kernel<<<1, 512, 0, stream>>>(eid, perm, ofs);
  build_kernel<<<T_TOK, 256, 0, stream>>>(h, score, perm, hb, xp);

  const int MT = T_TOK / BM;  // 16

  // shared gate -> gu[:, 0:F)
  dim3 gsh(FDIM / BN, MT);
  gemm_kernel<short, false><<<gsh, 256, 0, stream>>>(
      hb, HDIM, sg, 0, FDIM, gu, 2*FDIM, 0, nullptr, MT, T_TOK, HDIM, nullptr);
  // shared up -> gu[:, F:2F)
  gemm_kernel<short, false><<<gsh, 256, 0, stream>>>(
      hb, HDIM, su, 0, FDIM, gu, 2*FDIM, FDIM, nullptr, MT, T_TOK, HDIM, nullptr);
  // act
  act_kernel<<<(T_TOK * (size_t)FDIM) / (256 * 8), 256, 0, stream>>>(gu, act);
  // shared down -> out0 (direct write)
  dim3 gsd(HDIM / BN, MT);
  gemm_kernel<float, false><<<gsd, 256, 0, stream>>>(
      act, FDIM, sd, 0, HDIM, out0, HDIM, 0, nullptr, MT, T_TOK, FDIM, nullptr);

  // routed gate_up (grouped): xp @ gate_up_proj[e] -> gu (perm order)
  dim3 ggu(2 * FDIM / BN, NEXP * MT);
  gemm_kernel<short, false><<<ggu, 256, 0, stream>>>(
      xp, HDIM, gup, (long long)HDIM * 2 * FDIM, 2 * FDIM,
      gu, 2 * FDIM, 0, ofs, MT, T_TOK, HDIM, nullptr);
  // act
  act_kernel<<<(T_TOK * (size_t)FDIM) / (256 * 8), 256, 0, stream>>>(gu, act);
  // routed down (grouped, scatter-accumulate into out0)
  dim3 ggd(HDIM / BN, NEXP * MT);
  gemm_kernel<float, true><<<ggd, 256, 0, stream>>>(
      act, FDIM, dwn, (long long)FDIM * HDIM, HDIM,
      out0, HDIM, 0, ofs, MT, T_TOK, FDIM, perm);
}

// Round 2
// 635.258 us; speedup vs baseline: 1.2250x; 1.2250x over previous
//
#include <hip/hip_runtime.h>

#define T_TOK 2048
#define HDIM  2048
#define FDIM  4096
#define NEXP  8

#define BM 256
#define BN 64
#define BK 64
#define BKP 68
#define NT 256

typedef float f32x4 __attribute__((ext_vector_type(4)));
typedef float fvec4 __attribute__((ext_vector_type(4)));
typedef short s16x4 __attribute__((ext_vector_type(4)));
typedef short s16x8 __attribute__((ext_vector_type(8)));
typedef unsigned uint2v __attribute__((ext_vector_type(2)));

__device__ __forceinline__ short f2bf(float f) {
  union { float f; unsigned u; } c; c.f = f;
  unsigned r = c.u + 0x7FFFu + ((c.u >> 16) & 1u);
  return (short)(r >> 16);
}
__device__ __forceinline__ float bf2f(short h) {
  union { float f; unsigned u; } c; c.u = ((unsigned)(unsigned short)h) << 16;
  return c.f;
}
__device__ __forceinline__ unsigned cvtpk(float lo, float hi) {
  unsigned r;
  asm("v_cvt_pk_bf16_f32 %0, %1, %2" : "=v"(r) : "v"(lo), "v"(hi));
  return r;
}

#define GLL16(gsrc, ldst) \
  __builtin_amdgcn_global_load_lds((const __attribute__((address_space(1))) void*)(gsrc), \
                                   (__attribute__((address_space(3))) void*)(ldst), 16, 0, 0)

// ---------------- router: logits + top1 + sigmoid score ----------------
__global__ __launch_bounds__(256) void router_kernel(
    const float* __restrict__ h, const float* __restrict__ rw,
    float* __restrict__ logits, int* __restrict__ eid, float* __restrict__ score)
{
  int tok  = blockIdx.x * 4 + (threadIdx.x >> 6);
  int lane = threadIdx.x & 63;
  float a[8] = {0.f,0.f,0.f,0.f,0.f,0.f,0.f,0.f};
  const float* hp = h + (size_t)tok * HDIM;
  for (int i = lane; i < HDIM; i += 64) {
    float hv = hp[i];
    const fvec4* wp = (const fvec4*)(rw + (size_t)i * NEXP);
    fvec4 w0 = wp[0], w1 = wp[1];
    a[0] += hv * w0.x; a[1] += hv * w0.y; a[2] += hv * w0.z; a[3] += hv * w0.w;
    a[4] += hv * w1.x; a[5] += hv * w1.y; a[6] += hv * w1.z; a[7] += hv * w1.w;
  }
  #pragma unroll
  for (int e = 0; e < 8; e++) {
    #pragma unroll
    for (int off = 32; off; off >>= 1)
      a[e] += __shfl_xor(a[e], off, 64);
  }
  if (lane == 0) {
    float best = a[0]; int bi = 0;
    #pragma unroll
    for (int e = 1; e < 8; e++) if (a[e] > best) { best = a[e]; bi = e; }
    #pragma unroll
    for (int e = 0; e < 8; e++) logits[(size_t)tok * NEXP + e] = a[e];
    eid[tok] = bi;
    score[tok] = 1.0f / (1.0f + __expf(-best));
  }
}

// ---------------- stable counting sort of tokens by expert ----------------
__global__ __launch_bounds__(512) void sort_kernel(
    const int* __restrict__ eid, int* __restrict__ perm, int* __restrict__ ofs)
{
  __shared__ int s_cnt[8];
  __shared__ int s_off[9];
  int w = threadIdx.x >> 6, lane = threadIdx.x & 63;
  int cnt = 0;
  for (int b = 0; b < T_TOK; b += 64) {
    int id = eid[b + lane];
    unsigned long long m = __ballot(id == w);
    cnt += __popcll(m);
  }
  if (lane == 0) s_cnt[w] = cnt;
  __syncthreads();
  if (threadIdx.x == 0) {
    int o = 0;
    for (int e = 0; e < 8; e++) { s_off[e] = o; o += s_cnt[e]; }
    s_off[8] = o;
    for (int e = 0; e < 9; e++) ofs[e] = s_off[e];
  }
  __syncthreads();
  int pos = s_off[w];
  for (int b = 0; b < T_TOK; b += 64) {
    int tokidx = b + lane;
    int id = eid[tokidx];
    unsigned long long m = __ballot(id == w);
    if (id == w) {
      int p = pos + __popcll(m & ((1ull << lane) - 1ull));
      perm[p] = tokidx;
    }
    pos += __popcll(m);
  }
}

// ---------------- build bf16 h and permuted+scaled x ----------------
__global__ __launch_bounds__(256) void build_kernel(
    const float* __restrict__ h, const float* __restrict__ score,
    const int* __restrict__ perm, short* __restrict__ hb, short* __restrict__ xp)
{
  int row = blockIdx.x;
  int t = threadIdx.x;
  const fvec4* s1 = (const fvec4*)(h + (size_t)row * HDIM);
  for (int j = t; j < HDIM/4; j += 256) {
    fvec4 v = s1[j];
    s16x4 o = { f2bf(v.x), f2bf(v.y), f2bf(v.z), f2bf(v.w) };
    *(s16x4*)(hb + (size_t)row * HDIM + j*4) = o;
  }
  int tok = perm[row];
  float s = score[tok];
  const fvec4* s2 = (const fvec4*)(h + (size_t)tok * HDIM);
  for (int j = t; j < HDIM/4; j += 256) {
    fvec4 v = s2[j];
    s16x4 o = { f2bf(v.x*s), f2bf(v.y*s), f2bf(v.z*s), f2bf(v.w*s) };
    *(s16x4*)(xp + (size_t)row * HDIM + j*4) = o;
  }
}

// ---------------- unified MoE GEMM ----------------
// MODE 0: fused gate-up: two K-passes (B0=gate, B1=up), epilogue silu(g)*u -> bf16 C
// MODE 1: down-proj, fp32 store
// MODE 2: down-proj, fp32 scatter-accumulate via perm
// A bf16 [M,K] row-major; B fp32 [K,N] row-major per group.
template<int MODE>
__global__ __launch_bounds__(NT, 2) void moe_gemm(
    const short* __restrict__ A, int lda,
    const float* __restrict__ B0, const float* __restrict__ B1,
    long long bstride, int ldb,
    void* __restrict__ Cv, int ldc,
    const int* __restrict__ gofs, int mt_per_g, int K,
    const int* __restrict__ perm)
{
  __shared__ short sA[BM * BK];
  __shared__ short sB[BN * BKP];
  int g  = blockIdx.y / mt_per_g;
  int mt = blockIdx.y % mt_per_g;
  int r0 = 0, r1 = T_TOK;
  if (gofs) { r0 = gofs[g]; r1 = gofs[g+1]; }
  int row0 = r0 + mt * BM;
  if (row0 >= r1) return;
  int rows = r1 - row0; if (rows > BM) rows = BM;
  const float* Bg = B0 + (size_t)g * (size_t)bstride;
  const float* Bu = (MODE == 0) ? (B1 + (size_t)g * (size_t)bstride) : nullptr;
  int n0 = blockIdx.x * BN;

  int t = threadIdx.x;
  int lane = t & 63, w = t >> 6;
  int wrow = w * 64;
  int l16 = lane & 15, lh = lane >> 4;
  int s_rloc = lane >> 3, s_c = lane & 7;   // A-stage lane mapping
  int bcg = t & 15, bkb = t >> 4;           // B-stage mapping

  f32x4 zero4 = {0.f, 0.f, 0.f, 0.f};
  f32x4 acc[4][4];
  #pragma unroll
  for (int m = 0; m < 4; m++)
    #pragma unroll
    for (int n = 0; n < 4; n++) acc[m][n] = zero4;
  s16x4 sgate[4][4];

  const int NPASS = (MODE == 0) ? 2 : 1;
  for (int pass = 0; pass < NPASS; pass++) {
    const float* Bp = (pass == 0) ? Bg : Bu;
    for (int k0 = 0; k0 < K; k0 += BK) {
      if (pass + k0) __syncthreads();
      // ---- A stage: global_load_lds x8, swizzle folded into source addr ----
      #pragma unroll
      for (int i = 0; i < 8; i++) {
        int rbase = (w * 8 + i) * 8;
        int row = rbase + s_rloc;
        const short* src = A + (size_t)(row0 + row) * lda + (k0 + ((s_c ^ (row & 7)) << 3));
        GLL16(src, sA + rbase * BK);
      }
      // ---- B stage: fp32 -> bf16 (cvt_pk), 4x4 register transpose ----
      {
        const float* bp = Bp + (size_t)(k0 + bkb * 4) * ldb + n0 + bcg * 4;
        fvec4 f0 = *(const fvec4*)(bp);
        fvec4 f1 = *(const fvec4*)(bp + ldb);
        fvec4 f2 = *(const fvec4*)(bp + 2 * (size_t)ldb);
        fvec4 f3 = *(const fvec4*)(bp + 3 * (size_t)ldb);
        #pragma unroll
        for (int i2 = 0; i2 < 4; i2++) {
          uint2v o;
          o.x = cvtpk(f0[i2], f1[i2]);
          o.y = cvtpk(f2[i2], f3[i2]);
          *(uint2v*)(&sB[(bcg * 4 + i2) * BKP + bkb * 4]) = o;
        }
      }
      __syncthreads();
      // ---- compute ----
      #pragma unroll
      for (int kk = 0; kk < BK; kk += 32) {
        s16x8 aF[4], bF[4];
        #pragma unroll
        for (int m = 0; m < 4; m++) {
          int row = wrow + m * 16 + l16;
          int slot = ((kk >> 3) + lh) ^ (row & 7);
          aF[m] = *(const s16x8*)(&sA[row * BK + slot * 8]);
        }
        #pragma unroll
        for (int n = 0; n < 4; n++) {
          int col = n * 16 + l16;
          int kb = kk + lh * 8;
          s16x4 lo = *(const s16x4*)(&sB[col * BKP + kb]);
          s16x4 hi = *(const s16x4*)(&sB[col * BKP + kb + 4]);
          bF[n] = __builtin_shufflevector(lo, hi, 0, 1, 2, 3, 4, 5, 6, 7);
        }
        #pragma unroll
        for (int m = 0; m < 4; m++)
          #pragma unroll
          for (int n = 0; n < 4; n++)
            acc[m][n] = __builtin_amdgcn_mfma_f32_16x16x32_bf16(aF[m], bF[n], acc[m][n], 0, 0, 0);
      }
    }
    if (MODE == 0 && pass == 0) {
      // silu(gate) -> packed bf16, reset acc for up-pass
      #pragma unroll
      for (int m = 0; m < 4; m++)
        #pragma unroll
        for (int n = 0; n < 4; n++) {
          #pragma unroll
          for (int r = 0; r < 4; r++) {
            float gv = acc[m][n][r];
            sgate[m][n][r] = f2bf(gv / (1.0f + __expf(-gv)));
          }
          acc[m][n] = zero4;
        }
    }
  }
  // ---- epilogue ----
  #pragma unroll
  for (int m = 0; m < 4; m++) {
    #pragma unroll
    for (int r = 0; r < 4; r++) {
      int lr = wrow + m * 16 + lh * 4 + r;
      if (lr >= rows) continue;
      size_t grow = (MODE == 2) ? (size_t)perm[row0 + lr] : (size_t)(row0 + lr);
      size_t base = grow * (size_t)ldc + n0;
      #pragma unroll
      for (int n = 0; n < 4; n++) {
        int col = n * 16 + l16;
        float v = acc[m][n][r];
        if constexpr (MODE == 0) {
          ((short*)Cv)[base + col] = f2bf(bf2f(sgate[m][n][r]) * v);
        } else if constexpr (MODE == 1) {
          ((float*)Cv)[base + col] = v;
        } else {
          ((float*)Cv)[base + col] += v;
        }
      }
    }
  }
}

// ---------------- launch ----------------
extern "C" void kernel_launch(void* const* d_in, const int* in_sizes, int n_in,
                              void* d_out, int out_size, void* d_ws, size_t ws_size,
                              hipStream_t stream)
{
  const float* h   = (const float*)d_in[0];
  const float* rw  = (const float*)d_in[1];
  const float* gup = (const float*)d_in[2];
  const float* dwn = (const float*)d_in[3];
  const float* sg  = (const float*)d_in[4];
  const float* su  = (const float*)d_in[5];
  const float* sd  = (const float*)d_in[6];
  float* out0   = (float*)d_out;                       // [T, H]
  float* logits = out0 + (size_t)T_TOK * HDIM;         // [T, E]

  char* ws = (char*)d_ws;
  int*   eid    = (int*)ws;                  // 2048 ints
  float* score  = (float*)(ws + 8192);       // 2048 floats
  int*   perm   = (int*)(ws + 16384);        // 2048 ints
  int*   ofs    = (int*)(ws + 24576);        // 9 ints
  short* hb     = (short*)(ws + 32768);                 // [T, H] bf16
  short* xp     = hb + (size_t)T_TOK * HDIM;            // [T, H] bf16 (perm+scaled)
  short* act_sh = xp + (size_t)T_TOK * HDIM;            // [T, F] bf16
  short* act_rt = act_sh + (size_t)T_TOK * FDIM;        // [T, F] bf16 (perm space)
  // + BM*FDIM*2 bytes of slack after act_rt for last-tile overreads

  router_kernel<<<T_TOK/4, 256, 0, stream>>>(h, rw, logits, eid, score);
  sort_kernel<<<1, 512, 0, stream>>>(eid, perm, ofs);
  build_kernel<<<T_TOK, 256, 0, stream>>>(h, score, perm, hb, xp);

  const int MT = T_TOK / BM;   // 8

  // shared gate+up fused -> act_sh
  dim3 g_gu_sh(FDIM / BN, MT);
  moe_gemm<0><<<g_gu_sh, NT, 0, stream>>>(
      hb, HDIM, sg, su, 0, FDIM, act_sh, FDIM, nullptr, MT, HDIM, nullptr);
  // shared down -> out0 (store)
  dim3 g_dn_sh(HDIM / BN, MT);
  moe_gemm<1><<<g_dn_sh, NT, 0, stream>>>(
      act_sh, FDIM, sd, nullptr, 0, HDIM, out0, HDIM, nullptr, MT, FDIM, nullptr);
  // routed gate+up fused (grouped) -> act_rt (perm space)
  dim3 g_gu_rt(FDIM / BN, NEXP * MT);
  moe_gemm<0><<<g_gu_rt, NT, 0, stream>>>(
      xp, HDIM, gup, gup + FDIM, (long long)HDIM * 2 * FDIM, 2 * FDIM,
      act_rt, FDIM, ofs, MT, HDIM, nullptr);
  // routed down (grouped, scatter-accumulate into out0)
  dim3 g_dn_rt(HDIM / BN, NEXP * MT);
  moe_gemm<2><<<g_dn_rt, NT, 0, stream>>>(
      act_rt, FDIM, dwn, nullptr, (long long)FDIM * HDIM, HDIM,
      out0, HDIM, ofs, MT, FDIM, perm);
}

// Round 3
// 608.787 us; speedup vs baseline: 1.2783x; 1.0435x over previous
//
#include <hip/hip_runtime.h>

#define T_TOK 2048
#define HDIM  2048
#define FDIM  4096
#define NEXP  8

#define BM 128
#define BN 64
#define BK 64
#define BKP 68
#define NT 256

typedef float f32x4 __attribute__((ext_vector_type(4)));
typedef float fvec4 __attribute__((ext_vector_type(4)));
typedef short s16x4 __attribute__((ext_vector_type(4)));
typedef short s16x8 __attribute__((ext_vector_type(8)));
typedef unsigned uint2v __attribute__((ext_vector_type(2)));

__device__ __forceinline__ short f2bf(float f) {
  union { float f; unsigned u; } c; c.f = f;
  unsigned r = c.u + 0x7FFFu + ((c.u >> 16) & 1u);
  return (short)(r >> 16);
}
__device__ __forceinline__ float bf2f(short h) {
  union { float f; unsigned u; } c; c.u = ((unsigned)(unsigned short)h) << 16;
  return c.f;
}
__device__ __forceinline__ unsigned cvtpk(float lo, float hi) {
  unsigned r;
  asm("v_cvt_pk_bf16_f32 %0, %1, %2" : "=v"(r) : "v"(lo), "v"(hi));
  return r;
}

#define GLL16(gsrc, ldst) \
  __builtin_amdgcn_global_load_lds((const __attribute__((address_space(1))) void*)(gsrc), \
                                   (__attribute__((address_space(3))) void*)(ldst), 16, 0, 0)

// ---------------- router: logits + top1 + sigmoid score ----------------
__global__ __launch_bounds__(256) void router_kernel(
    const float* __restrict__ h, const float* __restrict__ rw,
    float* __restrict__ logits, int* __restrict__ eid, float* __restrict__ score)
{
  int tok  = blockIdx.x * 4 + (threadIdx.x >> 6);
  int lane = threadIdx.x & 63;
  float a[8] = {0.f,0.f,0.f,0.f,0.f,0.f,0.f,0.f};
  const float* hp = h + (size_t)tok * HDIM;
  for (int i = lane; i < HDIM; i += 64) {
    float hv = hp[i];
    const fvec4* wp = (const fvec4*)(rw + (size_t)i * NEXP);
    fvec4 w0 = wp[0], w1 = wp[1];
    a[0] += hv * w0.x; a[1] += hv * w0.y; a[2] += hv * w0.z; a[3] += hv * w0.w;
    a[4] += hv * w1.x; a[5] += hv * w1.y; a[6] += hv * w1.z; a[7] += hv * w1.w;
  }
  #pragma unroll
  for (int e = 0; e < 8; e++) {
    #pragma unroll
    for (int off = 32; off; off >>= 1)
      a[e] += __shfl_xor(a[e], off, 64);
  }
  if (lane == 0) {
    float best = a[0]; int bi = 0;
    #pragma unroll
    for (int e = 1; e < 8; e++) if (a[e] > best) { best = a[e]; bi = e; }
    #pragma unroll
    for (int e = 0; e < 8; e++) logits[(size_t)tok * NEXP + e] = a[e];
    eid[tok] = bi;
    score[tok] = 1.0f / (1.0f + __expf(-best));
  }
}

// ---------------- stable counting sort of tokens by expert ----------------
__global__ __launch_bounds__(512) void sort_kernel(
    const int* __restrict__ eid, int* __restrict__ perm, int* __restrict__ ofs)
{
  __shared__ int s_cnt[8];
  __shared__ int s_off[9];
  int w = threadIdx.x >> 6, lane = threadIdx.x & 63;
  int cnt = 0;
  for (int b = 0; b < T_TOK; b += 64) {
    int id = eid[b + lane];
    unsigned long long m = __ballot(id == w);
    cnt += __popcll(m);
  }
  if (lane == 0) s_cnt[w] = cnt;
  __syncthreads();
  if (threadIdx.x == 0) {
    int o = 0;
    for (int e = 0; e < 8; e++) { s_off[e] = o; o += s_cnt[e]; }
    s_off[8] = o;
    for (int e = 0; e < 9; e++) ofs[e] = s_off[e];
  }
  __syncthreads();
  int pos = s_off[w];
  for (int b = 0; b < T_TOK; b += 64) {
    int tokidx = b + lane;
    int id = eid[tokidx];
    unsigned long long m = __ballot(id == w);
    if (id == w) {
      int p = pos + __popcll(m & ((1ull << lane) - 1ull));
      perm[p] = tokidx;
    }
    pos += __popcll(m);
  }
}

// ---------------- build bf16 h and permuted+scaled x ----------------
__global__ __launch_bounds__(256) void build_kernel(
    const float* __restrict__ h, const float* __restrict__ score,
    const int* __restrict__ perm, short* __restrict__ hb, short* __restrict__ xp)
{
  int row = blockIdx.x;
  int t = threadIdx.x;
  const fvec4* s1 = (const fvec4*)(h + (size_t)row * HDIM);
  for (int j = t; j < HDIM/4; j += 256) {
    fvec4 v = s1[j];
    s16x4 o = { f2bf(v.x), f2bf(v.y), f2bf(v.z), f2bf(v.w) };
    *(s16x4*)(hb + (size_t)row * HDIM + j*4) = o;
  }
  int tok = perm[row];
  float s = score[tok];
  const fvec4* s2 = (const fvec4*)(h + (size_t)tok * HDIM);
  for (int j = t; j < HDIM/4; j += 256) {
    fvec4 v = s2[j];
    s16x4 o = { f2bf(v.x*s), f2bf(v.y*s), f2bf(v.z*s), f2bf(v.w*s) };
    *(s16x4*)(xp + (size_t)row * HDIM + j*4) = o;
  }
}

// ---------------- unified MoE GEMM, 2-phase double-buffered ----------------
// MODE 0: fused gate-up: tiles [0,KT)=gate(B0), [KT,2KT)=up(B1); epi silu(g)*u -> bf16
// MODE 1: down-proj, fp32 store
// MODE 2: down-proj, fp32 read-modify-write accumulate via perm rows
template<int MODE>
__global__ __launch_bounds__(NT, 3) void moe_gemm(
    const short* __restrict__ A, int lda,
    const float* __restrict__ B0, const float* __restrict__ B1,
    long long bstride, int ldb,
    void* __restrict__ Cv, int ldc,
    const int* __restrict__ gofs, int mt_per_g, int K,
    const int* __restrict__ perm)
{
  __shared__ short sA[2][BM * BK];
  __shared__ short sB[2][BN * BKP];
  int g  = blockIdx.y / mt_per_g;
  int mt = blockIdx.y % mt_per_g;
  int r0 = 0, r1 = T_TOK;
  if (gofs) { r0 = gofs[g]; r1 = gofs[g+1]; }
  int row0 = r0 + mt * BM;
  if (row0 >= r1) return;
  int rows = r1 - row0; if (rows > BM) rows = BM;
  const float* Bg = B0 + (size_t)g * (size_t)bstride;
  const float* Bu = (MODE == 0) ? (B1 + (size_t)g * (size_t)bstride) : nullptr;
  int n0 = blockIdx.x * BN;

  int tid = threadIdx.x;
  int lane = tid & 63, w = tid >> 6;
  int wr = (w >> 1) * 64, wc = (w & 1) * 32;
  int l16 = lane & 15, lh = lane >> 4;

  // A-stage mapping: per gll i: 8 rows starting at (w*4+i)*8
  int arow_in = lane >> 3;            // 0..7 within row-octet
  int aslot   = lane & 7;             // k-chunk
  int akoff   = ((aslot ^ arow_in) << 3);   // swizzled k offset (shorts)
  const short* aBase[4];
  #pragma unroll
  for (int i = 0; i < 4; i++) {
    int row = (w * 4 + i) * 8 + arow_in;
    int growc = row0 + row; if (growc > T_TOK - 1) growc = T_TOK - 1;
    aBase[i] = A + (size_t)growc * lda + akoff;
  }
  // B-stage mapping
  int bcg = tid & 15, bkb = tid >> 4;   // cols bcg*4.., k rows bkb*4..

  const int KT = K / BK;
  const int NTILES = (MODE == 0) ? 2 * KT : KT;

  f32x4 zero4 = {0.f, 0.f, 0.f, 0.f};
  f32x4 acc[4][2];
  #pragma unroll
  for (int m = 0; m < 4; m++) { acc[m][0] = zero4; acc[m][1] = zero4; }
  s16x4 sgate[4][2];
  fvec4 Breg[4];

  auto stage_issue = [&](int tt, int bb) {
    int k0 = (tt & (KT - 1)) * BK;
    const float* Bp = (MODE == 0 && tt >= KT) ? Bu : Bg;
    const float* bp = Bp + (size_t)(k0 + bkb * 4) * ldb + n0 + bcg * 4;
    Breg[0] = *(const fvec4*)(bp);
    Breg[1] = *(const fvec4*)(bp + ldb);
    Breg[2] = *(const fvec4*)(bp + 2 * (size_t)ldb);
    Breg[3] = *(const fvec4*)(bp + 3 * (size_t)ldb);
    #pragma unroll
    for (int i = 0; i < 4; i++) {
      GLL16(aBase[i] + k0, &sA[bb][(w * 4 + i) * 8 * BK]);
    }
  };
  auto stage_write = [&](int bb) {
    #pragma unroll
    for (int i2 = 0; i2 < 4; i2++) {
      uint2v o;
      o.x = cvtpk(Breg[0][i2], Breg[1][i2]);
      o.y = cvtpk(Breg[2][i2], Breg[3][i2]);
      *(uint2v*)(&sB[bb][(bcg * 4 + i2) * BKP + bkb * 4]) = o;
    }
  };
  auto compute = [&](int bb) {
    const short* sa = sA[bb];
    const short* sb = sB[bb];
    __builtin_amdgcn_s_setprio(1);
    #pragma unroll
    for (int kk = 0; kk < BK; kk += 32) {
      s16x8 aF[4], bF[2];
      #pragma unroll
      for (int m = 0; m < 4; m++) {
        int row = wr + m * 16 + l16;
        int slot = ((kk >> 3) + lh) ^ (l16 & 7);
        aF[m] = *(const s16x8*)(&sa[row * BK + slot * 8]);
      }
      #pragma unroll
      for (int n = 0; n < 2; n++) {
        int col = wc + n * 16 + l16;
        int kb = kk + lh * 8;
        s16x4 lo = *(const s16x4*)(&sb[col * BKP + kb]);
        s16x4 hi = *(const s16x4*)(&sb[col * BKP + kb + 4]);
        bF[n] = __builtin_shufflevector(lo, hi, 0, 1, 2, 3, 4, 5, 6, 7);
      }
      #pragma unroll
      for (int m = 0; m < 4; m++)
        #pragma unroll
        for (int n = 0; n < 2; n++)
          acc[m][n] = __builtin_amdgcn_mfma_f32_16x16x32_bf16(aF[m], bF[n], acc[m][n], 0, 0, 0);
    }
    __builtin_amdgcn_s_setprio(0);
  };

  // ---- prologue ----
  stage_issue(0, 0);
  stage_write(0);
  asm volatile("s_waitcnt vmcnt(0)" ::: "memory");
  asm volatile("s_waitcnt lgkmcnt(0)" ::: "memory");
  __builtin_amdgcn_s_barrier();

  // ---- main pipeline ----
  int buf = 0;
  for (int tt = 0; tt < NTILES; ++tt) {
    bool has_next = (tt + 1 < NTILES);
    if (has_next) stage_issue(tt + 1, buf ^ 1);
    compute(buf);
    if (MODE == 0 && tt == KT - 1) {
      #pragma unroll
      for (int m = 0; m < 4; m++)
        #pragma unroll
        for (int n = 0; n < 2; n++) {
          #pragma unroll
          for (int r = 0; r < 4; r++) {
            float gv = acc[m][n][r];
            sgate[m][n][r] = f2bf(gv / (1.0f + __expf(-gv)));
          }
          acc[m][n] = zero4;
        }
    }
    if (has_next) {
      stage_write(buf ^ 1);
      asm volatile("s_waitcnt vmcnt(0)" ::: "memory");
      asm volatile("s_waitcnt lgkmcnt(0)" ::: "memory");
      __builtin_amdgcn_s_barrier();
      buf ^= 1;
    }
  }

  // ---- epilogue ----
  #pragma unroll
  for (int m = 0; m < 4; m++) {
    #pragma unroll
    for (int r = 0; r < 4; r++) {
      int lr = wr + m * 16 + lh * 4 + r;
      if (lr >= rows) continue;
      size_t grow = (MODE == 2) ? (size_t)perm[row0 + lr] : (size_t)(row0 + lr);
      size_t base = grow * (size_t)ldc + n0;
      #pragma unroll
      for (int n = 0; n < 2; n++) {
        int col = wc + n * 16 + l16;
        float v = acc[m][n][r];
        if constexpr (MODE == 0) {
          ((short*)Cv)[base + col] = f2bf(bf2f(sgate[m][n][r]) * v);
        } else if constexpr (MODE == 1) {
          ((float*)Cv)[base + col] = v;
        } else {
          ((float*)Cv)[base + col] += v;
        }
      }
    }
  }
}

// ---------------- launch ----------------
extern "C" void kernel_launch(void* const* d_in, const int* in_sizes, int n_in,
                              void* d_out, int out_size, void* d_ws, size_t ws_size,
                              hipStream_t stream)
{
  const float* h   = (const float*)d_in[0];
  const float* rw  = (const float*)d_in[1];
  const float* gup = (const float*)d_in[2];
  const float* dwn = (const float*)d_in[3];
  const float* sg  = (const float*)d_in[4];
  const float* su  = (const float*)d_in[5];
  const float* sd  = (const float*)d_in[6];
  float* out0   = (float*)d_out;                       // [T, H]
  float* logits = out0 + (size_t)T_TOK * HDIM;         // [T, E]

  char* ws = (char*)d_ws;
  int*   eid    = (int*)ws;                  // 2048 ints
  float* score  = (float*)(ws + 8192);       // 2048 floats
  int*   perm   = (int*)(ws + 16384);        // 2048 ints
  int*   ofs    = (int*)(ws + 24576);        // 9 ints
  short* hb     = (short*)(ws + 32768);                 // [T, H] bf16
  short* xp     = hb + (size_t)T_TOK * HDIM;            // [T, H] bf16 (perm+scaled)
  short* act_sh = xp + (size_t)T_TOK * HDIM;            // [T, F] bf16
  short* act_rt = act_sh + (size_t)T_TOK * FDIM;        // [T, F] bf16 (perm space)

  router_kernel<<<T_TOK/4, 256, 0, stream>>>(h, rw, logits, eid, score);
  sort_kernel<<<1, 512, 0, stream>>>(eid, perm, ofs);
  build_kernel<<<T_TOK, 256, 0, stream>>>(h, score, perm, hb, xp);

  const int MT = T_TOK / BM;   // 16

  // shared gate+up fused -> act_sh
  dim3 g_gu_sh(FDIM / BN, MT);
  moe_gemm<0><<<g_gu_sh, NT, 0, stream>>>(
      hb, HDIM, sg, su, 0, FDIM, act_sh, FDIM, nullptr, MT, HDIM, nullptr);
  // shared down -> out0 (store)
  dim3 g_dn_sh(HDIM / BN, MT);
  moe_gemm<1><<<g_dn_sh, NT, 0, stream>>>(
      act_sh, FDIM, sd, nullptr, 0, HDIM, out0, HDIM, nullptr, MT, FDIM, nullptr);
  // routed gate+up fused (grouped) -> act_rt (perm space)
  dim3 g_gu_rt(FDIM / BN, NEXP * MT);
  moe_gemm<0><<<g_gu_rt, NT, 0, stream>>>(
      xp, HDIM, gup, gup + FDIM, (long long)HDIM * 2 * FDIM, 2 * FDIM,
      act_rt, FDIM, ofs, MT, HDIM, nullptr);
  // routed down (grouped, accumulate into out0)
  dim3 g_dn_rt(HDIM / BN, NEXP * MT);
  moe_gemm<2><<<g_dn_rt, NT, 0, stream>>>(
      act_rt, FDIM, dwn, nullptr, (long long)FDIM * HDIM, HDIM,
      out0, HDIM, ofs, MT, FDIM, perm);
}